// Round 13
// baseline (217.537 us; speedup 1.0000x reference)
//
#include <hip/hip_runtime.h>

#define NNODE 50000
#define NEDGE 800000
#define NTOT  (NEDGE + NNODE)   // 850000 edges incl. self loops
#define NCHUNK 196              // ceil(50000/256)
#define NGEMM 782               // 64-row x 256-col blocks, A staged once
#define NB_FUSED 1248           // interleave: bid%3==2 -> hist (h<=415), else gemm

typedef __attribute__((ext_vector_type(8))) short bf16x8;
typedef __attribute__((ext_vector_type(4))) float f32x4;
union U4B8 { uint4 u; bf16x8 b; };

// ---- bf16 helpers (storage-only; all math in fp32) ----
__device__ __forceinline__ unsigned short f2bf(float f) {
  union { float f; unsigned u; } v; v.f = f;
  unsigned r = v.u + 0x7FFFu + ((v.u >> 16) & 1u);   // RN-even
  return (unsigned short)(r >> 16);
}
__device__ __forceinline__ float bflo(unsigned u) {
  union { unsigned u; float f; } v; v.u = u << 16; return v.f;
}
__device__ __forceinline__ float bfhi(unsigned u) {
  union { unsigned u; float f; } v; v.u = u & 0xFFFF0000u; return v.f;
}
__device__ __forceinline__ unsigned packbf(float a, float b) {
  return (unsigned)f2bf(a) | ((unsigned)f2bf(b) << 16);
}

// ---- prep: W1 -> bf16 transposed [256][128] + zero deg (one dispatch) ----
__global__ __launch_bounds__(256) void k_prep(const float* __restrict__ W1,
                                              unsigned short* __restrict__ W1bT,
                                              int* __restrict__ deg) {
  const int b = (int)blockIdx.x;
  if (b < 32) {
    int flat = b * 256 + threadIdx.x;   // 8192 total
    int k = flat >> 6, c4 = (flat & 63) << 2;
    float4 v = *(const float4*)(W1 + k * 256 + c4);
    W1bT[(c4 + 0) * 128 + k] = f2bf(v.x);
    W1bT[(c4 + 1) * 128 + k] = f2bf(v.y);
    W1bT[(c4 + 2) * 128 + k] = f2bf(v.z);
    W1bT[(c4 + 3) * 128 + k] = f2bf(v.w);
  } else {
    int i = (b - 32) * 256 + threadIdx.x;
    if (i < NNODE) deg[i] = 0;
  }
}

// ---- fused MFMA GEMM + degree histogram, ROUND-ROBIN interleaved ---------
// bid%3==2: histogram block (2048 edges, 8 atomics in flight per thread)
// else:     GEMM block 64 rows x 256 cols (A staged+frag'd once, 2 head passes)
__global__ __launch_bounds__(256) void k_gemm_deg(
    const float* __restrict__ x, const unsigned short* __restrict__ W1bT,
    const float* __restrict__ a_s1, const float* __restrict__ a_d1,
    unsigned short* __restrict__ h1b, float* __restrict__ als1,
    float* __restrict__ ald1, const int* __restrict__ ei,
    int* __restrict__ deg, int* __restrict__ rank) {
  __shared__ unsigned short xs[64 * 136];   // 17408 B; reused as transpose tb
  const int bid = (int)blockIdx.x;
  const int t = threadIdx.x;
  if (bid % 3 == 2) {
    // ---- histogram role: edges [h*2048, (h+1)*2048), strided by 256 ----
    const int h = bid / 3;
    const int i0 = h * 2048 + t;
#pragma unroll
    for (int u = 0; u < 8; ++u) {
      int i = i0 + u * 256;
      if (i < NTOT) {
        int d = (i < NEDGE) ? ei[NEDGE + i] : (i - NEDGE);
        rank[i] = atomicAdd(deg + d, 1);   // rank within dst bucket
      }
    }
    return;
  }
  const int gid = bid - bid / 3;            // gemm block index
  if (gid >= NGEMM) return;
  const int grow0 = gid * 64;
  // stage A once: 64x128 fp32 -> bf16 LDS
#pragma unroll
  for (int i = 0; i < 8; ++i) {
    int f = t + i * 256;
    int row = f >> 5, c4 = (f & 31) << 2;
    int gr = grow0 + row;
    float4 v = make_float4(0.f, 0.f, 0.f, 0.f);
    if (gr < NNODE) v = *(const float4*)(x + gr * 128 + c4);
    *(uint2*)(xs + row * 136 + c4) = make_uint2(packbf(v.x, v.y), packbf(v.z, v.w));
  }
  const int wid = t >> 6, lane = t & 63;
  const int wrow = (wid >> 1) * 32;         // row half
  const int c_lo = lane & 15, g = lane >> 4;
  __syncthreads();
  // A-frags once (identical for both head passes)
  U4B8 afr[2][4];
#pragma unroll
  for (int mr = 0; mr < 2; ++mr)
#pragma unroll
    for (int ks = 0; ks < 4; ++ks)
      afr[mr][ks].u = *(const uint4*)(xs + (wrow + mr * 16 + c_lo) * 136 + ks * 32 + g * 8);
  __syncthreads();   // all waves done reading xs -> safe to reuse as tb
  unsigned short* tb = xs + wid * 2176;     // 32 x 68 shorts per wave

#pragma unroll
  for (int hpass = 0; hpass < 2; ++hpass) {
    const int head = hpass * 2 + (wid & 1);
    U4B8 bfr[4][4];
#pragma unroll
    for (int nr = 0; nr < 4; ++nr) {
      int c = head * 64 + nr * 16 + c_lo;
#pragma unroll
      for (int ks = 0; ks < 4; ++ks)
        bfr[nr][ks].u = *(const uint4*)(W1bT + c * 128 + ks * 32 + g * 8);
    }
    f32x4 acc[2][4];
#pragma unroll
    for (int mr = 0; mr < 2; ++mr)
#pragma unroll
      for (int nr = 0; nr < 4; ++nr) acc[mr][nr] = (f32x4){0.f, 0.f, 0.f, 0.f};
#pragma unroll
    for (int ks = 0; ks < 4; ++ks)
#pragma unroll
      for (int mr = 0; mr < 2; ++mr)
#pragma unroll
        for (int nr = 0; nr < 4; ++nr)
          acc[mr][nr] = __builtin_amdgcn_mfma_f32_16x16x32_bf16(
              afr[mr][ks].b, bfr[nr][ks].b, acc[mr][nr], 0, 0, 0);
    // ---- attention-logit epilogue (full head dot within this wave) ----
    float as_v[4], ad_v[4];
#pragma unroll
    for (int nr = 0; nr < 4; ++nr) {
      as_v[nr] = a_s1[head * 64 + nr * 16 + c_lo];
      ad_v[nr] = a_d1[head * 64 + nr * 16 + c_lo];
    }
    float ps[2][4], pd[2][4];
#pragma unroll
    for (int mr = 0; mr < 2; ++mr)
#pragma unroll
      for (int r = 0; r < 4; ++r) {
        float s = 0.f, dsum = 0.f;
#pragma unroll
        for (int nr = 0; nr < 4; ++nr) {
          s += acc[mr][nr][r] * as_v[nr];
          dsum += acc[mr][nr][r] * ad_v[nr];
        }
        ps[mr][r] = s; pd[mr][r] = dsum;
      }
#pragma unroll
    for (int m = 1; m < 16; m <<= 1)
#pragma unroll
      for (int mr = 0; mr < 2; ++mr)
#pragma unroll
        for (int r = 0; r < 4; ++r) {
          ps[mr][r] += __shfl_xor(ps[mr][r], m, 64);
          pd[mr][r] += __shfl_xor(pd[mr][r], m, 64);
        }
    if (c_lo == 0) {
#pragma unroll
      for (int mr = 0; mr < 2; ++mr)
#pragma unroll
        for (int r = 0; r < 4; ++r) {
          int node = grow0 + wrow + mr * 16 + g * 4 + r;
          if (node < NNODE) {
            als1[node * 4 + head] = ps[mr][r];
            ald1[node * 4 + head] = pd[mr][r];
          }
        }
    }
    // ---- store h1b via wave-private LDS transpose (stride 68) ----
#pragma unroll
    for (int mr = 0; mr < 2; ++mr)
#pragma unroll
      for (int nr = 0; nr < 4; ++nr)
#pragma unroll
        for (int r = 0; r < 4; ++r)
          tb[(mr * 16 + g * 4 + r) * 68 + nr * 16 + c_lo] = f2bf(acc[mr][nr][r]);
#pragma unroll
    for (int i = 0; i < 4; ++i) {
      int unit = i * 64 + lane;
      int row = unit >> 3, cS = (unit & 7) * 8;
      int node = grow0 + wrow + row;
      if (node < NNODE) {
        uint4 v = *(const uint4*)(tb + row * 68 + cS);
        *(uint4*)(h1b + (size_t)node * 256 + head * 64 + cS) = v;
      }
    }
  }
}

// ---- CSR scan: 256-node chunks, wave-shfl scan (196 blocks) ----
__global__ __launch_bounds__(256) void k_scan1(const int* __restrict__ deg,
                                               int* __restrict__ rowp,
                                               int* __restrict__ csum) {
  __shared__ int ws[4];
  const int t = threadIdx.x, lane = t & 63, wid = t >> 6;
  const int idx = (int)blockIdx.x * 256 + t;
  int sv = (idx < NNODE) ? deg[idx] : 0;
#pragma unroll
  for (int off = 1; off < 64; off <<= 1) {
    int n = __shfl_up(sv, off, 64);
    if (lane >= off) sv += n;
  }
  if (lane == 63) ws[wid] = sv;
  __syncthreads();
  int add = 0;
#pragma unroll
  for (int p = 0; p < 3; ++p) if (wid > p) add += ws[p];
  sv += add;
  if (idx < NNODE) rowp[idx + 1] = sv;
  if (t == 255) csum[blockIdx.x] = sv;
}

// ---- fused scan-finalize + scatter (every block redundantly scans csum) ---
__global__ __launch_bounds__(256) void k_scanscatter(
    const int* __restrict__ ei, const int* __restrict__ rowp,
    const int* __restrict__ csum, const int* __restrict__ rank,
    int* __restrict__ rowf, int* __restrict__ esrc) {
  __shared__ int boff[256];
  const int t = threadIdx.x;
  if (t < 64) {
    const int c0 = t * 4;
    int s0 = (c0 + 0 < NCHUNK) ? csum[c0 + 0] : 0;
    int s1 = (c0 + 1 < NCHUNK) ? csum[c0 + 1] : 0;
    int s2 = (c0 + 2 < NCHUNK) ? csum[c0 + 2] : 0;
    int s3 = (c0 + 3 < NCHUNK) ? csum[c0 + 3] : 0;
    int local = s0 + s1 + s2 + s3;
    int sv = local;
#pragma unroll
    for (int off = 1; off < 64; off <<= 1) {
      int n = __shfl_up(sv, off, 64);
      if (t >= off) sv += n;
    }
    int excl = sv - local;
    boff[c0 + 0] = excl;
    boff[c0 + 1] = excl + s0;
    boff[c0 + 2] = excl + s0 + s1;
    boff[c0 + 3] = excl + s0 + s1 + s2;
  }
  __syncthreads();
  const int i = (int)blockIdx.x * 256 + t;
  if (i < NNODE) {
    rowf[i + 1] = rowp[i + 1] + boff[i >> 8];
    if (i == 0) rowf[0] = 0;
  }
  if (i < NTOT) {
    int s, d;
    if (i < NEDGE) { s = ei[i]; d = ei[NEDGE + i]; }
    else           { s = i - NEDGE; d = s; }
    int base = (d == 0) ? 0 : rowp[d] + boff[(d - 1) >> 8];
    esrc[base + rank[i]] = s;
  }
}

// ------- layer-1 aggregate + bias + relu + layer-2 linear/logits -------
// one wave per dst node; half-wave per edge (2 chains), 1-deep esrc prefetch.
__global__ __launch_bounds__(256) void k_agg1(
    const unsigned short* __restrict__ h1b, const float* __restrict__ als1,
    const float* __restrict__ ald1, const int* __restrict__ rowptr,
    const int* __restrict__ esrc, const float* __restrict__ b1,
    const float* __restrict__ W2, const float* __restrict__ a_s2,
    const float* __restrict__ a_d2, float4* __restrict__ h2c) {
  const int w = threadIdx.x >> 6, lane = threadIdx.x & 63;
  const int d = (int)blockIdx.x * 4 + w;           // grid = 12500
  const int half = lane >> 5, cl = lane & 31;
  const int head = cl >> 3;
  const float ald = ald1[d * 4 + head];
  const int begin = rowptr[d], end = rowptr[d + 1];
  float acc[8];
#pragma unroll
  for (int i = 0; i < 8; ++i) acc[i] = 0.f;
  float S = 0.f;

  int j = begin + half;
  int s = (j < end) ? esrc[j] : -1;
  while (s >= 0) {
    const uint4 hv = *(const uint4*)(h1b + (size_t)s * 256 + cl * 8);
    float e = als1[s * 4 + head] + ald;
    int jn = j + 2;
    int sn = (jn < end) ? esrc[jn] : -1;
    e = fmaxf(e, 0.2f * e);               // leaky relu
    float wgt = __expf(e);
    S += wgt;
    acc[0] += wgt * bflo(hv.x); acc[1] += wgt * bfhi(hv.x);
    acc[2] += wgt * bflo(hv.y); acc[3] += wgt * bfhi(hv.y);
    acc[4] += wgt * bflo(hv.z); acc[5] += wgt * bfhi(hv.z);
    acc[6] += wgt * bflo(hv.w); acc[7] += wgt * bfhi(hv.w);
    j = jn; s = sn;
  }
  // combine the two half-waves
  S += __shfl_xor(S, 32, 64);
#pragma unroll
  for (int i = 0; i < 8; ++i) acc[i] += __shfl_xor(acc[i], 32, 64);

  const float inv = 1.f / S;
  const int c0 = cl * 8;
  float4 ba = *(const float4*)(b1 + c0);
  float4 bb = *(const float4*)(b1 + c0 + 4);
  float bias[8] = {ba.x, ba.y, ba.z, ba.w, bb.x, bb.y, bb.z, bb.w};
  float4 w0 = *(const float4*)(W2 + c0 * 2);
  float4 w1 = *(const float4*)(W2 + c0 * 2 + 4);
  float4 w2 = *(const float4*)(W2 + c0 * 2 + 8);
  float4 w3 = *(const float4*)(W2 + c0 * 2 + 12);
  float wa[16] = {w0.x, w0.y, w0.z, w0.w, w1.x, w1.y, w1.z, w1.w,
                  w2.x, w2.y, w2.z, w2.w, w3.x, w3.y, w3.z, w3.w};
  float p0 = 0.f, p1 = 0.f;
#pragma unroll
  for (int i = 0; i < 8; ++i) {
    float v = acc[i] * inv + bias[i];
    v = v > 0.f ? v : 0.f;
    p0 += v * wa[2 * i];
    p1 += v * wa[2 * i + 1];
  }
#pragma unroll
  for (int m = 1; m < 32; m <<= 1) {
    p0 += __shfl_xor(p0, m, 64);
    p1 += __shfl_xor(p1, m, 64);
  }
  if (lane == 0) {
    h2c[d] = make_float4(p0, p1,
                         p0 * a_s2[0] + p1 * a_s2[1],
                         p0 * a_d2[0] + p1 * a_d2[1]);
  }
}

// ------- layer-2 aggregate -> out (4 threads per dst, shfl combine) -------
__global__ __launch_bounds__(256) void k_agg2(
    const float4* __restrict__ h2c, const int* __restrict__ rowptr,
    const int* __restrict__ esrc, const float* __restrict__ b2,
    float* __restrict__ out) {
  const int t = threadIdx.x;
  const int g = t & 3;
  const int d = (int)blockIdx.x * 64 + (t >> 2);
  if (d >= NNODE) return;
  const float ald = h2c[d].w;
  const int begin = rowptr[d], end = rowptr[d + 1];
  float S = 0.f, a0 = 0.f, a1 = 0.f;
  for (int j = begin + g; j < end; j += 4) {
    int s = esrc[j];
    float4 v = h2c[s];
    float e = v.z + ald;
    e = fmaxf(e, 0.2f * e);
    float wgt = __expf(e);
    S += wgt;
    a0 += wgt * v.x;
    a1 += wgt * v.y;
  }
  S  += __shfl_xor(S, 1, 64);  S  += __shfl_xor(S, 2, 64);
  a0 += __shfl_xor(a0, 1, 64); a0 += __shfl_xor(a0, 2, 64);
  a1 += __shfl_xor(a1, 1, 64); a1 += __shfl_xor(a1, 2, 64);
  if (g == 0) {
    float inv = 1.f / S;
    out[d * 2 + 0] = a0 * inv + b2[0];
    out[d * 2 + 1] = a1 * inv + b2[1];
  }
}

static inline size_t algn(size_t x) { return (x + 255) & ~(size_t)255; }

extern "C" void kernel_launch(void* const* d_in, const int* in_sizes, int n_in,
                              void* d_out, int out_size, void* d_ws, size_t ws_size,
                              hipStream_t stream) {
  const float* x    = (const float*)d_in[0];
  const int*   ei   = (const int*)d_in[1];
  const float* W1   = (const float*)d_in[2];
  const float* a_s1 = (const float*)d_in[3];
  const float* a_d1 = (const float*)d_in[4];
  const float* b1   = (const float*)d_in[5];
  const float* W2   = (const float*)d_in[6];
  const float* a_s2 = (const float*)d_in[7];
  const float* a_d2 = (const float*)d_in[8];
  const float* b2   = (const float*)d_in[9];
  float* out = (float*)d_out;

  char* w = (char*)d_ws;
  size_t o = 0;
  unsigned short* h1b = (unsigned short*)(w + o); o += algn((size_t)NNODE * 256 * 2);
  unsigned short* W1bT = (unsigned short*)(w + o); o += algn((size_t)256 * 128 * 2);
  float* als1 = (float*)(w + o); o += algn((size_t)NNODE * 4 * 4);
  float* ald1 = (float*)(w + o); o += algn((size_t)NNODE * 4 * 4);
  int*   deg  = (int*)(w + o);   o += algn((size_t)NNODE * 4);
  int*   rowp = (int*)(w + o);   o += algn((size_t)(NNODE + 1) * 4);
  int*   rowf = (int*)(w + o);   o += algn((size_t)(NNODE + 1) * 4);
  int*   rank = (int*)(w + o);   o += algn((size_t)NTOT * 4);
  int*   esrc = (int*)(w + o);   o += algn((size_t)NTOT * 4);
  int*   csum = (int*)(w + o);   o += 1024;
  float4* h2c = (float4*)(w + o); o += algn((size_t)NNODE * 16);
  (void)ws_size; (void)n_in; (void)in_sizes; (void)out_size;

  k_prep<<<dim3(32 + 196), dim3(256), 0, stream>>>(W1, W1bT, deg);
  k_gemm_deg<<<dim3(NB_FUSED), dim3(256), 0, stream>>>(
      x, W1bT, a_s1, a_d1, h1b, als1, ald1, ei, deg, rank);
  k_scan1<<<dim3(NCHUNK), dim3(256), 0, stream>>>(deg, rowp, csum);
  k_scanscatter<<<dim3((NTOT + 255) / 256), dim3(256), 0, stream>>>(
      ei, rowp, csum, rank, rowf, esrc);
  k_agg1<<<dim3(12500), dim3(256), 0, stream>>>(h1b, als1, ald1, rowf, esrc, b1,
                                                W2, a_s2, a_d2, h2c);
  k_agg2<<<dim3((NNODE + 63) / 64), dim3(256), 0, stream>>>(h2c, rowf, esrc, b2, out);
}